// Round 5
// baseline (224.145 us; speedup 1.0000x reference)
//
#include <hip/hip_runtime.h>
#include <math.h>

#define NN 8192
#define CC 4096
#define SLOTS 64
#define BLK 256

// out = sum_c cnt_c * value_c * NUM_POS / N^2 ; NUM_POS=4, N=8192
#define SCALE (4.0f / (8192.0f * 8192.0f))

__global__ void init_kernel(int* __restrict__ counts) {
    int i = blockIdx.x * blockDim.x + threadIdx.x;
    if (i < CC) counts[i] = 0;
}

__global__ void build_index(const int* __restrict__ label,
                            int* __restrict__ counts,
                            int* __restrict__ lists) {
    int i = blockIdx.x * blockDim.x + threadIdx.x;
    if (i < NN) {
        int lab = label[i];
        int pos = atomicAdd(&counts[lab], 1);
        if (pos < SLOTS) lists[lab * SLOTS + pos] = i;
    }
}

// Sequential streaming touch of all of feat: pulls it into the memory-side
// Infinity Cache (L3) so the following gather is L3-resident. Coalesced
// grid-stride; per-thread sums stored (cheap) so loads can't be DCE'd.
__global__ __launch_bounds__(BLK) void warm(const float4* __restrict__ f4,
                                            float* __restrict__ dummy) {
    int idx = blockIdx.x * BLK + threadIdx.x;          // 2048*256 = 524288 threads
    float s = 0.f;
    #pragma unroll
    for (int i = 0; i < 16; ++i) {                     // 16 * 524288 = 8388608 float4 = 128 MB
        float4 v = f4[(size_t)i * 524288 + idx];
        s += v.x + v.y + v.z + v.w;
    }
    dummy[idx] = s;
}

// One block per class. Wave w owns float4 slots w*256 + i*64 + lane (i<4).
// Row loop processes 4 rows per iteration with all 16 loads in flight.
// Tail rows duplicate row 0 (MSHR-merged) with weight 0.
__global__ __launch_bounds__(BLK) void class_loss(const float* __restrict__ feat,
                                                  const int* __restrict__ counts,
                                                  const int* __restrict__ lists,
                                                  float* __restrict__ value) {
    int c = blockIdx.x;
    int t = threadIdx.x;
    int lane = t & 63, w = t >> 6;

    __shared__ int s_cnt;
    __shared__ int s_rows[SLOTS];
    if (t == 0) s_cnt = counts[c];
    if (t < SLOTS) s_rows[t] = lists[c * SLOTS + t];  // junk past cnt unused
    __syncthreads();

    int cnt = s_cnt;
    if (cnt == 0) {
        if (t == 0) value[c] = 0.0f;
        return;
    }
    int m = cnt < SLOTS ? cnt : SLOTS;

    float4 a[4];
    #pragma unroll
    for (int i = 0; i < 4; ++i) a[i] = make_float4(0.f, 0.f, 0.f, 0.f);

    int base_slot = w * 256 + lane;
    int r0 = s_rows[0];

    for (int k = 0; k < m; k += 4) {
        int ra = s_rows[k];
        int rb = (k + 1 < m) ? s_rows[k + 1] : r0;
        int rc = (k + 2 < m) ? s_rows[k + 2] : r0;
        int rd = (k + 3 < m) ? s_rows[k + 3] : r0;
        float fb = (k + 1 < m) ? 1.f : 0.f;
        float fc = (k + 2 < m) ? 1.f : 0.f;
        float fd = (k + 3 < m) ? 1.f : 0.f;
        const float4* pa = (const float4*)(feat + (size_t)ra * CC);
        const float4* pb = (const float4*)(feat + (size_t)rb * CC);
        const float4* pc = (const float4*)(feat + (size_t)rc * CC);
        const float4* pd = (const float4*)(feat + (size_t)rd * CC);

        float4 va[4], vb[4], vc4[4], vd[4];
        #pragma unroll
        for (int i = 0; i < 4; ++i) va[i] = pa[base_slot + i * 64];
        #pragma unroll
        for (int i = 0; i < 4; ++i) vb[i] = pb[base_slot + i * 64];
        #pragma unroll
        for (int i = 0; i < 4; ++i) vc4[i] = pc[base_slot + i * 64];
        #pragma unroll
        for (int i = 0; i < 4; ++i) vd[i] = pd[base_slot + i * 64];

        #pragma unroll
        for (int i = 0; i < 4; ++i) {
            a[i].x += va[i].x + fb * vb[i].x + fc * vc4[i].x + fd * vd[i].x;
            a[i].y += va[i].y + fb * vb[i].y + fc * vc4[i].y + fd * vd[i].y;
            a[i].z += va[i].z + fb * vb[i].z + fc * vc4[i].z + fd * vd[i].z;
            a[i].w += va[i].w + fb * vb[i].w + fc * vc4[i].w + fd * vd[i].w;
        }
    }

    float inv = 1.0f / (float)cnt;
    float vals[16];
    #pragma unroll
    for (int i = 0; i < 4; ++i) {
        vals[i * 4 + 0] = a[i].x * inv;
        vals[i * 4 + 1] = a[i].y * inv;
        vals[i * 4 + 2] = a[i].z * inv;
        vals[i * 4 + 3] = a[i].w * inv;
    }

    __shared__ float s_red[4];
    __shared__ float s_bcast;
    __shared__ float s_vc;

    // --- block max ---
    float wm = vals[0];
    #pragma unroll
    for (int j = 1; j < 16; ++j) wm = fmaxf(wm, vals[j]);
    #pragma unroll
    for (int off = 1; off < 64; off <<= 1) wm = fmaxf(wm, __shfl_xor(wm, off, 64));
    if (lane == 0) s_red[w] = wm;
    __syncthreads();
    if (t == 0) s_bcast = fmaxf(fmaxf(s_red[0], s_red[1]), fmaxf(s_red[2], s_red[3]));
    __syncthreads();
    float M = s_bcast;

    // --- block sum of exp(v - M); owner deposits v at column c ---
    int s_idx = c >> 2, cj = c & 3;
    int ow = s_idx >> 8, orem = s_idx & 255;
    int oi = orem >> 6, ol = orem & 63;
    float se = 0.f;
    #pragma unroll
    for (int j = 0; j < 16; ++j) se += __expf(vals[j] - M);
    #pragma unroll
    for (int off = 1; off < 64; off <<= 1) se += __shfl_xor(se, off, 64);
    if (lane == 0) s_red[w] = se;
    if (t == ow * 64 + ol) s_vc = vals[oi * 4 + cj];
    __syncthreads();

    if (t == 0) {
        float S = s_red[0] + s_red[1] + s_red[2] + s_red[3];
        value[c] = (float)cnt * (M + __logf(S) - s_vc);
    }
}

__global__ __launch_bounds__(BLK) void finalize(const float* __restrict__ value,
                                                float* __restrict__ out) {
    int t = threadIdx.x;
    const float4* v4 = (const float4*)value;
    float s = 0.f;
    #pragma unroll
    for (int i = 0; i < CC / 4 / BLK; ++i) {
        float4 v = v4[i * BLK + t];
        s += v.x + v.y + v.z + v.w;
    }
    #pragma unroll
    for (int off = 1; off < 64; off <<= 1) s += __shfl_xor(s, off, 64);
    __shared__ float s_red[4];
    int lane = t & 63, wv = t >> 6;
    if (lane == 0) s_red[wv] = s;
    __syncthreads();
    if (t == 0) out[0] = (s_red[0] + s_red[1] + s_red[2] + s_red[3]) * SCALE;
}

extern "C" void kernel_launch(void* const* d_in, const int* in_sizes, int n_in,
                              void* d_out, int out_size, void* d_ws, size_t ws_size,
                              hipStream_t stream) {
    const float* feat = (const float*)d_in[0];
    const int* label = (const int*)d_in[1];
    float* out = (float*)d_out;

    int* counts = (int*)d_ws;                          // CC ints
    int* lists = counts + CC;                          // CC * SLOTS ints
    float* value = (float*)(lists + CC * SLOTS);       // CC floats
    float* dummy = value + CC;                         // 524288 floats (2 MB)

    init_kernel<<<(CC + BLK - 1) / BLK, BLK, 0, stream>>>(counts);
    build_index<<<(NN + BLK - 1) / BLK, BLK, 0, stream>>>(label, counts, lists);
    warm<<<2048, BLK, 0, stream>>>((const float4*)feat, dummy);
    class_loss<<<CC, BLK, 0, stream>>>(feat, counts, lists, value);
    finalize<<<1, BLK, 0, stream>>>(value, out);
}

// Round 6
// 201.102 us; speedup vs baseline: 1.1146x; 1.1146x over previous
//
#include <hip/hip_runtime.h>
#include <math.h>

#define NN 8192
#define CC 4096
#define SLOTS 64
#define BLK 256
#define NSPLIT 16   // 16 column splits of 256 cols (1 KB) per class; one WAVE per (class,split)

// out = sum_c cnt_c * value_c * NUM_POS / N^2 ; NUM_POS=4, N=8192
#define SCALE (4.0f / (8192.0f * 8192.0f))

__global__ void init_kernel(int* __restrict__ counts, float* __restrict__ out) {
    int i = blockIdx.x * blockDim.x + threadIdx.x;
    if (i < CC) counts[i] = 0;
    if (i == 0) out[0] = 0.0f;
}

__global__ void build_index(const int* __restrict__ label,
                            int* __restrict__ counts,
                            int* __restrict__ lists) {
    int i = blockIdx.x * blockDim.x + threadIdx.x;
    if (i < NN) {
        int lab = label[i];
        int pos = atomicAdd(&counts[lab], 1);
        if (pos < SLOTS) lists[lab * SLOTS + pos] = i;
    }
}

// Tiered gather: T loads issued back-to-back (single vmcnt drain), tail rows
// duplicate row 0 with weight 0 (dup loads are L2-merged, ~free).
template <int T>
__device__ inline float4 gather_sum(const float4* __restrict__ feat4,
                                    const int* __restrict__ rl, int m, int slot) {
    int r0 = rl[0];
    float4 v[T];
    #pragma unroll
    for (int k = 0; k < T; ++k) {
        int r = (k < m) ? rl[k] : r0;
        v[k] = feat4[(size_t)r * (CC / 4) + slot];
    }
    float4 a = make_float4(0.f, 0.f, 0.f, 0.f);
    #pragma unroll
    for (int k = 0; k < T; ++k) {
        float w = (k < m) ? 1.f : 0.f;
        a.x += w * v[k].x; a.y += w * v[k].y; a.z += w * v[k].z; a.w += w * v[k].w;
    }
    return a;
}

// One wave per (class c, split s). Lane l owns float4 slot s*64+l of each row,
// i.e. columns s*256 + 4*l + j. No LDS, no __syncthreads. Writes
// part[s*CC + c] = (M_s, S_s = sum exp(v-M_s), vc_s).
__global__ __launch_bounds__(BLK) void part_kernel(const float4* __restrict__ feat4,
                                                   const int* __restrict__ counts,
                                                   const int* __restrict__ lists,
                                                   float4* __restrict__ part) {
    int lane = threadIdx.x & 63;
    int wv = __builtin_amdgcn_readfirstlane(threadIdx.x >> 6);  // force scalar
    int task = blockIdx.x * 4 + wv;
    int c = task >> 4;
    int s = task & 15;

    int cnt = counts[c];            // uniform -> scalar load
    if (cnt == 0) return;           // wave-uniform exit; finalize skips these
    int m = cnt < SLOTS ? cnt : SLOTS;

    const int* rl = lists + c * SLOTS;
    int slot = s * 64 + lane;

    float4 acc;
    if (m <= 2)      acc = gather_sum<2>(feat4, rl, m, slot);
    else if (m <= 4) acc = gather_sum<4>(feat4, rl, m, slot);
    else if (m <= 8) acc = gather_sum<8>(feat4, rl, m, slot);
    else {
        acc = gather_sum<16>(feat4, rl, m, slot);
        for (int k = 16; k < m; ++k) {   // essentially never taken
            float4 v = feat4[(size_t)rl[k] * (CC / 4) + slot];
            acc.x += v.x; acc.y += v.y; acc.z += v.z; acc.w += v.w;
        }
    }

    float inv = 1.0f / (float)cnt;
    float mean[4] = {acc.x * inv, acc.y * inv, acc.z * inv, acc.w * inv};

    // wave max
    float M = fmaxf(fmaxf(mean[0], mean[1]), fmaxf(mean[2], mean[3]));
    #pragma unroll
    for (int off = 1; off < 64; off <<= 1) M = fmaxf(M, __shfl_xor(M, off, 64));

    // wave sum of exp
    float S = __expf(mean[0] - M) + __expf(mean[1] - M) +
              __expf(mean[2] - M) + __expf(mean[3] - M);
    #pragma unroll
    for (int off = 1; off < 64; off <<= 1) S += __shfl_xor(S, off, 64);

    // v at column c: owned by split c>>8, lane (c>>2)&63, component c&3
    float cand = mean[c & 3];
    float vcown = __shfl(cand, (c >> 2) & 63, 64);
    float vc = (s == (c >> 8)) ? vcown : 0.f;

    if (lane == 0) part[s * CC + c] = make_float4(M, S, vc, 0.f);
}

// Combine 16 splits per class (exact logsumexp merge), weight by cnt, reduce.
__global__ __launch_bounds__(BLK) void finalize(const float4* __restrict__ part,
                                                const int* __restrict__ counts,
                                                float* __restrict__ out) {
    int c = blockIdx.x * BLK + threadIdx.x;   // 16 blocks x 256 = 4096
    int cnt = counts[c];
    float contrib = 0.f;
    if (cnt > 0) {
        float4 p[NSPLIT];
        #pragma unroll
        for (int s = 0; s < NSPLIT; ++s) p[s] = part[s * CC + c];  // coalesced per s
        float M = p[0].x;
        #pragma unroll
        for (int s = 1; s < NSPLIT; ++s) M = fmaxf(M, p[s].x);
        float S = 0.f, vc = 0.f;
        #pragma unroll
        for (int s = 0; s < NSPLIT; ++s) {
            S += p[s].y * __expf(p[s].x - M);
            vc += p[s].z;   // non-owning splits contributed 0
        }
        contrib = (float)cnt * (M + __logf(S) - vc);
    }

    #pragma unroll
    for (int off = 1; off < 64; off <<= 1) contrib += __shfl_xor(contrib, off, 64);
    __shared__ float s_red[4];
    int lane = threadIdx.x & 63, w = threadIdx.x >> 6;
    if (lane == 0) s_red[w] = contrib;
    __syncthreads();
    if (threadIdx.x == 0)
        atomicAdd(out, (s_red[0] + s_red[1] + s_red[2] + s_red[3]) * SCALE);
}

extern "C" void kernel_launch(void* const* d_in, const int* in_sizes, int n_in,
                              void* d_out, int out_size, void* d_ws, size_t ws_size,
                              hipStream_t stream) {
    const float* feat = (const float*)d_in[0];
    const int* label = (const int*)d_in[1];
    float* out = (float*)d_out;

    int* counts = (int*)d_ws;                      // CC ints
    int* lists = counts + CC;                      // CC * SLOTS ints
    float4* part = (float4*)(lists + CC * SLOTS);  // NSPLIT * CC float4 (1 MB)

    init_kernel<<<(CC + BLK - 1) / BLK, BLK, 0, stream>>>(counts, out);
    build_index<<<(NN + BLK - 1) / BLK, BLK, 0, stream>>>(label, counts, lists);
    part_kernel<<<CC * NSPLIT / 4, BLK, 0, stream>>>((const float4*)feat, counts, lists, part);
    finalize<<<CC / BLK, BLK, 0, stream>>>(part, counts, out);
}